// Round 11
// baseline (205.426 us; speedup 1.0000x reference)
//
#include <hip/hip_runtime.h>

typedef unsigned short ushort_t;
typedef unsigned int uint_t;
typedef short short8 __attribute__((ext_vector_type(8)));
typedef float f32x4 __attribute__((ext_vector_type(4)));

namespace {

template<int CTRL, int RM>
__device__ __forceinline__ float dpp_mov0(float v) {
  return __int_as_float(__builtin_amdgcn_update_dpp(
      0, __float_as_int(v), CTRL, RM, 0xF, false));
}
template<int CTRL, int RM>
__device__ __forceinline__ float dpp_mov1(float v) {
  return __int_as_float(__builtin_amdgcn_update_dpp(
      0x3f800000, __float_as_int(v), CTRL, RM, 0xF, false));
}

__device__ __forceinline__ float rl(float v, int k) {
  return __int_as_float(__builtin_amdgcn_readlane(__float_as_int(v), k));
}

// A_bar apply via joint 2-var linear-recurrence DPP scan (HW-verified r1-r10,
// absmax <= 4.9e-4). Coefs hoisted (data-independent).
struct Hoist {
  float cs0, cs1, cs2, cs3, cs4, cs5;
  float gs0, gs1, gs2, gs3, gs4, gs5;
  float r, inv_d, hr, alpha, k2;
};

__device__ __forceinline__ Hoist make_hoist(float dt, int n) {
  float h = 0.5f * dt, fn = (float)n;
  float r = sqrtf(2.f * fn + 1.f);
  float d = 1.f + h * (fn + 1.f);
  float inv_d = 1.f / d;
  float g = (1.f - h * fn) * inv_d;
  float c = g - 1.f;
  Hoist H;
  H.r = r; H.inv_d = inv_d; H.hr = h * r;
  H.alpha = 1.f + h * fn;
  H.k2 = r * (2.f - d) * inv_d;
#define COEF_STEP(IDX, CTRL, RM)                                        \
  H.cs##IDX = c; H.gs##IDX = g;                                         \
  { float cP = dpp_mov0<CTRL, RM>(c);                                   \
    float gP = dpp_mov1<CTRL, RM>(g);                                   \
    c = fmaf(g, cP, c); g = g * gP; }
  COEF_STEP(0, 0x111, 0xF)
  COEF_STEP(1, 0x112, 0xF)
  COEF_STEP(2, 0x114, 0xF)
  COEF_STEP(3, 0x118, 0xF)
  COEF_STEP(4, 0x142, 0xA)
  COEF_STEP(5, 0x143, 0xC)
#undef COEF_STEP
  return H;
}

__device__ __forceinline__ float abar_apply(float x, const Hoist& H) {
  float w1 = H.r * x, w2 = H.k2 * x;
#define APPLY_STEP(IDX, CTRL, RM)                                       \
  { float w1P = dpp_mov0<CTRL, RM>(w1);                                 \
    float w2P = dpp_mov0<CTRL, RM>(w2);                                 \
    w2 = fmaf(H.cs##IDX, w1P, fmaf(H.gs##IDX, w2P, w2));                \
    w1 += w1P; }
  APPLY_STEP(0, 0x111, 0xF)
  APPLY_STEP(1, 0x112, 0xF)
  APPLY_STEP(2, 0x114, 0xF)
  APPLY_STEP(3, 0x118, 0xF)
  APPLY_STEP(4, 0x142, 0xA)
  APPLY_STEP(5, 0x143, 0xC)
#undef APPLY_STEP
  float tp = dpp_mov0<0x138, 0xF>(w2);           // wave_shr:1
  return H.inv_d * fmaf(-H.hr, w1 + tp, H.alpha * x);
}

template<int CTRL, int RM>
__device__ __forceinline__ void linrec_step(float& G, float& W) {
  float Wo = dpp_mov0<CTRL, RM>(W);
  float Go = dpp_mov1<CTRL, RM>(G);
  W = fmaf(G, Wo, W);
  G *= Go;
}
__device__ __forceinline__ float lhs_solve(float z, const Hoist& H) {
  float G = H.gs0, W = H.r * z * H.inv_d;
  linrec_step<0x111, 0xF>(G, W);
  linrec_step<0x112, 0xF>(G, W);
  linrec_step<0x114, 0xF>(G, W);
  linrec_step<0x118, 0xF>(G, W);
  linrec_step<0x142, 0xA>(G, W);
  linrec_step<0x143, 0xC>(G, W);
  float sp = dpp_mov0<0x138, 0xF>(W);
  return (z - H.hr * sp) * H.inv_d;
}

__device__ __forceinline__ float softplus_dt(float ldt) {
  return log1pf(expf(ldt)) + 1e-6f;
}

__device__ __forceinline__ void load_row_g(const float* __restrict__ base,
                                           float (&pc)[64]) {
  const float4* p4 = (const float4*)base;
  #pragma unroll
  for (int q = 0; q < 16; ++q) {
    float4 f = p4[q];
    pc[4*q+0] = f.x; pc[4*q+1] = f.y; pc[4*q+2] = f.z; pc[4*q+3] = f.w;
  }
}

__device__ __forceinline__ float qapply(const float (&pc)[64], float u) {
  float a0 = 0.f, a1 = 0.f, a2 = 0.f, a3 = 0.f;
  #pragma unroll
  for (int k = 0; k < 64; k += 4) {
    a0 = fmaf(pc[k + 0], rl(u, k + 0), a0);
    a1 = fmaf(pc[k + 1], rl(u, k + 1), a1);
    a2 = fmaf(pc[k + 2], rl(u, k + 2), a2);
    a3 = fmaf(pc[k + 3], rl(u, k + 3), a3);
  }
  return (a0 + a1) + (a2 + a3);
}

__device__ __forceinline__ float grow_matvec(const float* __restrict__ M,
                                             float u, int lane) {
  float a0 = 0.f, a1 = 0.f, a2 = 0.f, a3 = 0.f;
  const float4* m4 = (const float4*)(M + lane * 64);
  #pragma unroll
  for (int q = 0; q < 16; ++q) {
    float4 f = m4[q];
    a0 = fmaf(f.x, rl(u, 4 * q + 0), a0);
    a1 = fmaf(f.y, rl(u, 4 * q + 1), a1);
    a2 = fmaf(f.z, rl(u, 4 * q + 2), a2);
    a3 = fmaf(f.w, rl(u, 4 * q + 3), a3);
  }
  return (a0 + a1) + (a2 + a3);
}

// bf16 error-compensated split store into chunk-XOR-swizzled LDS (R7-verified)
__device__ __forceinline__ void split_store(float v, ushort_t* Hi,
                                            ushort_t* Lo, int row, int n) {
  uint_t uv = __float_as_uint(v);
  float hf = __uint_as_float(uv & 0xFFFF0000u);
  uint_t lv = __float_as_uint(v - hf);
  int idx = (row << 6) | (((n >> 3) ^ (row & 7)) << 3) | (n & 7);
  Hi[idx] = (ushort_t)(uv >> 16);
  Lo[idx] = (ushort_t)(lv >> 16);
}

__device__ __forceinline__ int frag_off(int row, int chunk) {
  return (row << 6) | ((chunk ^ (row & 7)) << 3);
}

// device-scope flag sync (all blocks co-resident by capacity -> no deadlock)
__device__ __forceinline__ void wait_cnt(const uint_t* f, uint_t tgt) {
  while (__hip_atomic_load(f, __ATOMIC_ACQUIRE, __HIP_MEMORY_SCOPE_AGENT) < tgt)
    __builtin_amdgcn_s_sleep(2);
}
__device__ __forceinline__ void signal_cnt(uint_t* f, int lane) {
  __threadfence();   // device-scope release of prior stores
  if (lane == 0)
    __hip_atomic_fetch_add(f, 1u, __ATOMIC_RELEASE, __HIP_MEMORY_SCOPE_AGENT);
}

} // namespace

// ONE kernel. Blocks 0-63 (wave 0 only): prep chains for column m.
//   s=32: A32c[n][m] (scatter) -> flags[0]
//   s=64: QROW[m][k] (coalesced) + A64RM[n][m] (scatter) -> flags[1]
//   then spin flags[1]==64, A128 col m = A64RM-row matvec, Q2ROW[m][k] -> flags[2]
// Blocks 64+ (d = bid-64): R7-verified main (V/U chains + MFMA epilogue);
//   w3 waits flags[0]; w2 waits flags[1] then flags[2]; w1 waits flags[2].
__global__ __launch_bounds__(256, 2) void hippo_fused(
    const float* __restrict__ B, const float* __restrict__ C,
    const float* __restrict__ Dv, const float* __restrict__ ldt_p,
    uint_t* __restrict__ flags, float* __restrict__ A32c,
    float* __restrict__ A64RM, float* __restrict__ QROW,
    float* __restrict__ Q2ROW, float* __restrict__ out) {
  const int bid = blockIdx.x;
  const int tau = threadIdx.x;
  const int lane = tau & 63;
  const int w = tau >> 6;

  if (bid < 64) {
    if (w != 0) return;                    // prep uses one wave; no barriers here
    const int m = bid;
    const float dt = softplus_dt(ldt_p[0]);
    const Hoist H = make_hoist(dt, lane);
    float x = (lane == m) ? 1.f : 0.f;
    #pragma unroll 1
    for (int s = 0; s < 32; ++s) x = abar_apply(x, H);
    A32c[lane * 64 + m] = x;               // A32 row-major (scatter)
    signal_cnt(&flags[0], lane);
    #pragma unroll 1
    for (int s = 0; s < 32; ++s) x = abar_apply(x, H);
    QROW[m * 64 + lane] = x;               // Q rows: QROW[m][k]=A64[k][m]
    A64RM[lane * 64 + m] = x;              // A64 row-major (scatter)
    signal_cnt(&flags[1], lane);
    wait_cnt(&flags[1], 64);               // all of A64 visible
    float pc[64];
    load_row_g(A64RM + lane * 64, pc);     // pc[k] = A64[lane][k]
    float x128 = qapply(pc, x);            // A128[lane][m] (x = A64 col m)
    Q2ROW[m * 64 + lane] = x128;           // Q2ROW[m][k] = A128[k][m]
    signal_cnt(&flags[2], lane);
    return;
  }

  __shared__ __align__(16) ushort_t Uh[32 * 64], Ulo[32 * 64];
  __shared__ __align__(16) ushort_t Vh[64 * 64], Vlo[64 * 64];
  const int d = bid - 64;
  const float dt = softplus_dt(ldt_p[0]);

  if (w == 0) {
    const Hoist H = make_hoist(dt, lane);
    float v = lhs_solve(dt * B[d * 64 + lane], H);
    #pragma unroll 1
    for (int j = 0; j < 32; ++j) {
      split_store(v, Vh, Vlo, j, lane);
      if (j < 31) v = abar_apply(v, H);
    }
  } else if (w == 3) {
    const Hoist H = make_hoist(dt, lane);
    float bb = lhs_solve(dt * B[d * 64 + lane], H);
    wait_cnt(&flags[0], 64);
    float v = grow_matvec(A32c, bb, lane);      // V32 = A32 * B_bar
    #pragma unroll 1
    for (int j = 32; j < 64; ++j) {
      split_store(v, Vh, Vlo, j, lane);
      if (j < 63) v = abar_apply(v, H);
    }
  } else if (w == 1) {
    float u = C[d * 64 + lane];
    wait_cnt(&flags[2], 64);
    float pc[64];
    load_row_g(Q2ROW + lane * 64, pc);          // pc[k] = Q2[lane][k]
    #pragma unroll 1
    for (int a = 0; a < 16; ++a) {
      split_store(u, Uh, Ulo, 2 * a, lane);
      if (a < 15) u = qapply(pc, u);
    }
  } else {  // w == 2
    float u0 = C[d * 64 + lane];
    wait_cnt(&flags[1], 64);
    float u = grow_matvec(QROW, u0, lane);      // u1 = Q u0
    wait_cnt(&flags[2], 64);
    float pc[64];
    load_row_g(Q2ROW + lane * 64, pc);
    #pragma unroll 1
    for (int a = 0; a < 16; ++a) {
      split_store(u, Uh, Ulo, 2 * a + 1, lane);
      if (a < 15) u = qapply(pc, u);
    }
  }
  __syncthreads();

  // MFMA epilogue (R7-verified): D(32x64) = U(32x64) . V(64x64)^T, bf16x2 split.
  const int it = w & 1;
  const int jp = w >> 1;
  const int arow = lane & 15;
  const int kg = lane >> 4;
  f32x4 acc0 = {0.f, 0.f, 0.f, 0.f};
  f32x4 acc1 = {0.f, 0.f, 0.f, 0.f};
  const int ia = (it << 4) + arow;
  const int jv0 = (jp << 5) + arow;
  const int jv1 = jv0 + 16;
  #pragma unroll
  for (int k0 = 0; k0 < 2; ++k0) {
    const int ci = (k0 << 2) + kg;
    short8 ah = *(const short8*)&Uh[frag_off(ia, ci)];
    short8 al = *(const short8*)&Ulo[frag_off(ia, ci)];
    short8 b0h = *(const short8*)&Vh[frag_off(jv0, ci)];
    short8 b0l = *(const short8*)&Vlo[frag_off(jv0, ci)];
    short8 b1h = *(const short8*)&Vh[frag_off(jv1, ci)];
    short8 b1l = *(const short8*)&Vlo[frag_off(jv1, ci)];
    acc0 = __builtin_amdgcn_mfma_f32_16x16x32_bf16(ah, b0h, acc0, 0, 0, 0);
    acc0 = __builtin_amdgcn_mfma_f32_16x16x32_bf16(al, b0h, acc0, 0, 0, 0);
    acc0 = __builtin_amdgcn_mfma_f32_16x16x32_bf16(ah, b0l, acc0, 0, 0, 0);
    acc1 = __builtin_amdgcn_mfma_f32_16x16x32_bf16(ah, b1h, acc1, 0, 0, 0);
    acc1 = __builtin_amdgcn_mfma_f32_16x16x32_bf16(al, b1h, acc1, 0, 0, 0);
    acc1 = __builtin_amdgcn_mfma_f32_16x16x32_bf16(ah, b1l, acc1, 0, 0, 0);
  }
  // C/D layout (m89-verified): col = lane&15, row = (lane>>4)*4 + reg.
  #pragma unroll
  for (int r = 0; r < 4; ++r) {
    const int i = (it << 4) + (kg << 2) + r;
    const int j0 = (jp << 5) + arow;
    float y0 = acc0[r];
    if (i == 0 && j0 == 0) y0 += Dv[d];
    out[((size_t)d << 11) + (i << 6) + j0] = y0;
    out[((size_t)d << 11) + (i << 6) + j0 + 16] = acc1[r];
  }
}

extern "C" void kernel_launch(void* const* d_in, const int* in_sizes, int n_in,
                              void* d_out, int out_size, void* d_ws, size_t ws_size,
                              hipStream_t stream) {
  const float* B   = (const float*)d_in[0];
  const float* C   = (const float*)d_in[1];
  const float* Dv  = (const float*)d_in[2];
  const float* ldt = (const float*)d_in[3];
  const int d_model = in_sizes[2];        // 1024

  char* ws = (char*)d_ws;
  uint_t* flags = (uint_t*)ws;                     // 256 B reserved
  float* A32c  = (float*)(ws + 256);               // 16 KiB
  float* A64RM = (float*)(ws + 256 + 16384);       // 16 KiB
  float* QROW  = (float*)(ws + 256 + 32768);       // 16 KiB
  float* Q2ROW = (float*)(ws + 256 + 49152);       // 16 KiB

  // zero the sync flags every call (capturable as a graph memset node)
  hipMemsetAsync(flags, 0, 256, stream);
  hippo_fused<<<64 + d_model, 256, 0, stream>>>(B, C, Dv, ldt, flags, A32c,
                                                A64RM, QROW, Q2ROW,
                                                (float*)d_out);
}

// Round 12
// 39.623 us; speedup vs baseline: 5.1845x; 5.1845x over previous
//
#include <hip/hip_runtime.h>

typedef unsigned short ushort_t;
typedef unsigned int uint_t;
typedef short short8 __attribute__((ext_vector_type(8)));
typedef float f32x4 __attribute__((ext_vector_type(4)));

namespace {

template<int CTRL, int RM>
__device__ __forceinline__ float dpp_mov0(float v) {
  return __int_as_float(__builtin_amdgcn_update_dpp(
      0, __float_as_int(v), CTRL, RM, 0xF, false));
}
template<int CTRL, int RM>
__device__ __forceinline__ float dpp_mov1(float v) {
  return __int_as_float(__builtin_amdgcn_update_dpp(
      0x3f800000, __float_as_int(v), CTRL, RM, 0xF, false));
}

__device__ __forceinline__ float rl(float v, int k) {
  return __int_as_float(__builtin_amdgcn_readlane(__float_as_int(v), k));
}

// A_bar apply via joint 2-var linear-recurrence DPP scan (HW-verified r1-r11,
// absmax <= 4.9e-4). Coefs hoisted (data-independent).
struct Hoist {
  float cs0, cs1, cs2, cs3, cs4, cs5;
  float gs0, gs1, gs2, gs3, gs4, gs5;
  float r, inv_d, hr, alpha, k2;
};

__device__ __forceinline__ Hoist make_hoist(float dt, int n) {
  float h = 0.5f * dt, fn = (float)n;
  float r = sqrtf(2.f * fn + 1.f);
  float d = 1.f + h * (fn + 1.f);
  float inv_d = 1.f / d;
  float g = (1.f - h * fn) * inv_d;
  float c = g - 1.f;
  Hoist H;
  H.r = r; H.inv_d = inv_d; H.hr = h * r;
  H.alpha = 1.f + h * fn;
  H.k2 = r * (2.f - d) * inv_d;
#define COEF_STEP(IDX, CTRL, RM)                                        \
  H.cs##IDX = c; H.gs##IDX = g;                                         \
  { float cP = dpp_mov0<CTRL, RM>(c);                                   \
    float gP = dpp_mov1<CTRL, RM>(g);                                   \
    c = fmaf(g, cP, c); g = g * gP; }
  COEF_STEP(0, 0x111, 0xF)
  COEF_STEP(1, 0x112, 0xF)
  COEF_STEP(2, 0x114, 0xF)
  COEF_STEP(3, 0x118, 0xF)
  COEF_STEP(4, 0x142, 0xA)
  COEF_STEP(5, 0x143, 0xC)
#undef COEF_STEP
  return H;
}

__device__ __forceinline__ float abar_apply(float x, const Hoist& H) {
  float w1 = H.r * x, w2 = H.k2 * x;
#define APPLY_STEP(IDX, CTRL, RM)                                       \
  { float w1P = dpp_mov0<CTRL, RM>(w1);                                 \
    float w2P = dpp_mov0<CTRL, RM>(w2);                                 \
    w2 = fmaf(H.cs##IDX, w1P, fmaf(H.gs##IDX, w2P, w2));                \
    w1 += w1P; }
  APPLY_STEP(0, 0x111, 0xF)
  APPLY_STEP(1, 0x112, 0xF)
  APPLY_STEP(2, 0x114, 0xF)
  APPLY_STEP(3, 0x118, 0xF)
  APPLY_STEP(4, 0x142, 0xA)
  APPLY_STEP(5, 0x143, 0xC)
#undef APPLY_STEP
  float tp = dpp_mov0<0x138, 0xF>(w2);           // wave_shr:1
  return H.inv_d * fmaf(-H.hr, w1 + tp, H.alpha * x);
}

template<int CTRL, int RM>
__device__ __forceinline__ void linrec_step(float& G, float& W) {
  float Wo = dpp_mov0<CTRL, RM>(W);
  float Go = dpp_mov1<CTRL, RM>(G);
  W = fmaf(G, Wo, W);
  G *= Go;
}
__device__ __forceinline__ float lhs_solve(float z, const Hoist& H) {
  float G = H.gs0, W = H.r * z * H.inv_d;
  linrec_step<0x111, 0xF>(G, W);
  linrec_step<0x112, 0xF>(G, W);
  linrec_step<0x114, 0xF>(G, W);
  linrec_step<0x118, 0xF>(G, W);
  linrec_step<0x142, 0xA>(G, W);
  linrec_step<0x143, 0xC>(G, W);
  float sp = dpp_mov0<0x138, 0xF>(W);
  return (z - H.hr * sp) * H.inv_d;
}

__device__ __forceinline__ float softplus_dt(float ldt) {
  return log1pf(expf(ldt)) + 1e-6f;
}

// Load M[lane][0..63] into 16 float4 REGISTERS and pin them there: each
// component is laundered through an opaque asm so the compiler can neither
// rematerialize the loads inside the serial loop nor demote to scratch.
// (R11 evidence: without this, VGPR_Count=48 -> compiler reloads per matvec.)
#define KEEP4(v) asm volatile("" : "+v"(v.x), "+v"(v.y), "+v"(v.z), "+v"(v.w))

__device__ __forceinline__ void load_row_pin(const float* __restrict__ base,
                                             float4 (&p)[16]) {
  const float4* p4 = (const float4*)base;
  #pragma unroll
  for (int q = 0; q < 16; ++q) p[q] = p4[q];
  #pragma unroll
  for (int q = 0; q < 16; ++q) KEEP4(p[q]);
}

// res[lane] = sum_k p[k/4][k%4]*u[k]; u distributed, broadcast via readlane.
__device__ __forceinline__ float qapply_pin(const float4 (&p)[16], float u) {
  float a0 = 0.f, a1 = 0.f, a2 = 0.f, a3 = 0.f;
  #pragma unroll
  for (int q = 0; q < 16; ++q) {
    a0 = fmaf(p[q].x, rl(u, 4 * q + 0), a0);
    a1 = fmaf(p[q].y, rl(u, 4 * q + 1), a1);
    a2 = fmaf(p[q].z, rl(u, 4 * q + 2), a2);
    a3 = fmaf(p[q].w, rl(u, 4 * q + 3), a3);
  }
  return (a0 + a1) + (a2 + a3);
}

// streaming matvec from global row (one float4 live at a time) — seeds only
__device__ __forceinline__ float grow_matvec(const float* __restrict__ M,
                                             float u, int lane) {
  float a0 = 0.f, a1 = 0.f, a2 = 0.f, a3 = 0.f;
  const float4* m4 = (const float4*)(M + lane * 64);
  #pragma unroll
  for (int q = 0; q < 16; ++q) {
    float4 f = m4[q];
    a0 = fmaf(f.x, rl(u, 4 * q + 0), a0);
    a1 = fmaf(f.y, rl(u, 4 * q + 1), a1);
    a2 = fmaf(f.z, rl(u, 4 * q + 2), a2);
    a3 = fmaf(f.w, rl(u, 4 * q + 3), a3);
  }
  return (a0 + a1) + (a2 + a3);
}

// bf16 error-compensated split store into chunk-XOR-swizzled LDS (R7-verified)
__device__ __forceinline__ void split_store(float v, ushort_t* Hi,
                                            ushort_t* Lo, int row, int n) {
  uint_t uv = __float_as_uint(v);
  float hf = __uint_as_float(uv & 0xFFFF0000u);
  uint_t lv = __float_as_uint(v - hf);
  int idx = (row << 6) | (((n >> 3) ^ (row & 7)) << 3) | (n & 7);
  Hi[idx] = (ushort_t)(uv >> 16);
  Lo[idx] = (ushort_t)(lv >> 16);
}

__device__ __forceinline__ int frag_off(int row, int chunk) {
  return (row << 6) | ((chunk ^ (row & 7)) << 3);
}

} // namespace

// Prep: block m chains e_m through 128 applies (R7-verified).
//   s=32 : col m of A32  -> row-major A32c (scatter)
//   s=64 : col m of A64  = Q-row m   -> QROW  (coalesced)
//   s=128: col m of A128 = Q^2-row m -> Q2ROW (coalesced)
__global__ __launch_bounds__(64) void hippo_pow(const float* __restrict__ ldt_p,
                                                float* __restrict__ A32c,
                                                float* __restrict__ QROW,
                                                float* __restrict__ Q2ROW) {
  const int lane = threadIdx.x;
  const int m = blockIdx.x;
  const float dt = softplus_dt(ldt_p[0]);
  const Hoist H = make_hoist(dt, lane);
  float x = (lane == m) ? 1.f : 0.f;
  #pragma unroll 1
  for (int s = 0; s < 32; ++s) x = abar_apply(x, H);
  A32c[lane * 64 + m] = x;
  #pragma unroll 1
  for (int s = 0; s < 32; ++s) x = abar_apply(x, H);
  QROW[m * 64 + lane] = x;
  #pragma unroll 1
  for (int s = 0; s < 64; ++s) x = abar_apply(x, H);
  Q2ROW[m * 64 + lane] = x;
}

// Main (R7 structure, register-pinned Q2 rows, no min-waves bound):
//  w0: V[0..31]; w3: V[32..63] (A32 seed); w1: U even (Q^2); w2: U odd.
//  Epilogue: 12 mfma_f32_16x16x32_bf16 per wave (bf16x2 split: hh+hl+lh).
__global__ __launch_bounds__(256) void hippo_main(
    const float* __restrict__ B, const float* __restrict__ C,
    const float* __restrict__ Dv, const float* __restrict__ ldt_p,
    const float* __restrict__ A32c, const float* __restrict__ QROW,
    const float* __restrict__ Q2ROW, float* __restrict__ out) {
  __shared__ __align__(16) ushort_t Uh[32 * 64], Ulo[32 * 64];
  __shared__ __align__(16) ushort_t Vh[64 * 64], Vlo[64 * 64];
  const int d = blockIdx.x;
  const int tau = threadIdx.x;
  const int lane = tau & 63;
  const int w = tau >> 6;
  const float dt = softplus_dt(ldt_p[0]);

  if (w == 0) {
    const Hoist H = make_hoist(dt, lane);
    float v = lhs_solve(dt * B[d * 64 + lane], H);
    #pragma unroll 1
    for (int j = 0; j < 32; ++j) {
      split_store(v, Vh, Vlo, j, lane);
      if (j < 31) v = abar_apply(v, H);
    }
  } else if (w == 3) {
    const Hoist H = make_hoist(dt, lane);
    float bb = lhs_solve(dt * B[d * 64 + lane], H);
    float v = grow_matvec(A32c, bb, lane);      // V32 = A32 * B_bar
    #pragma unroll 1
    for (int j = 32; j < 64; ++j) {
      split_store(v, Vh, Vlo, j, lane);
      if (j < 63) v = abar_apply(v, H);
    }
  } else if (w == 1) {
    float4 p[16];
    load_row_pin(Q2ROW + lane * 64, p);         // p = Q2[lane][:], PINNED
    float u = C[d * 64 + lane];
    #pragma unroll 1
    for (int a = 0; a < 16; ++a) {
      split_store(u, Uh, Ulo, 2 * a, lane);
      if (a < 15) u = qapply_pin(p, u);
    }
  } else {  // w == 2
    float u = grow_matvec(QROW, C[d * 64 + lane], lane);   // u1 = Q u0
    float4 p[16];
    load_row_pin(Q2ROW + lane * 64, p);
    #pragma unroll 1
    for (int a = 0; a < 16; ++a) {
      split_store(u, Uh, Ulo, 2 * a + 1, lane);
      if (a < 15) u = qapply_pin(p, u);
    }
  }
  __syncthreads();

  // MFMA epilogue (R7-verified): D(32x64) = U(32x64) . V(64x64)^T, bf16x2.
  const int it = w & 1;
  const int jp = w >> 1;
  const int arow = lane & 15;
  const int kg = lane >> 4;
  f32x4 acc0 = {0.f, 0.f, 0.f, 0.f};
  f32x4 acc1 = {0.f, 0.f, 0.f, 0.f};
  const int ia = (it << 4) + arow;
  const int jv0 = (jp << 5) + arow;
  const int jv1 = jv0 + 16;
  #pragma unroll
  for (int k0 = 0; k0 < 2; ++k0) {
    const int ci = (k0 << 2) + kg;
    short8 ah = *(const short8*)&Uh[frag_off(ia, ci)];
    short8 al = *(const short8*)&Ulo[frag_off(ia, ci)];
    short8 b0h = *(const short8*)&Vh[frag_off(jv0, ci)];
    short8 b0l = *(const short8*)&Vlo[frag_off(jv0, ci)];
    short8 b1h = *(const short8*)&Vh[frag_off(jv1, ci)];
    short8 b1l = *(const short8*)&Vlo[frag_off(jv1, ci)];
    acc0 = __builtin_amdgcn_mfma_f32_16x16x32_bf16(ah, b0h, acc0, 0, 0, 0);
    acc0 = __builtin_amdgcn_mfma_f32_16x16x32_bf16(al, b0h, acc0, 0, 0, 0);
    acc0 = __builtin_amdgcn_mfma_f32_16x16x32_bf16(ah, b0l, acc0, 0, 0, 0);
    acc1 = __builtin_amdgcn_mfma_f32_16x16x32_bf16(ah, b1h, acc1, 0, 0, 0);
    acc1 = __builtin_amdgcn_mfma_f32_16x16x32_bf16(al, b1h, acc1, 0, 0, 0);
    acc1 = __builtin_amdgcn_mfma_f32_16x16x32_bf16(ah, b1l, acc1, 0, 0, 0);
  }
  // C/D layout (m89-verified): col = lane&15, row = (lane>>4)*4 + reg.
  #pragma unroll
  for (int r = 0; r < 4; ++r) {
    const int i = (it << 4) + (kg << 2) + r;
    const int j0 = (jp << 5) + arow;
    float y0 = acc0[r];
    if (i == 0 && j0 == 0) y0 += Dv[d];
    out[((size_t)d << 11) + (i << 6) + j0] = y0;
    out[((size_t)d << 11) + (i << 6) + j0 + 16] = acc1[r];
  }
}

extern "C" void kernel_launch(void* const* d_in, const int* in_sizes, int n_in,
                              void* d_out, int out_size, void* d_ws, size_t ws_size,
                              hipStream_t stream) {
  const float* B   = (const float*)d_in[0];
  const float* C   = (const float*)d_in[1];
  const float* Dv  = (const float*)d_in[2];
  const float* ldt = (const float*)d_in[3];
  const int d_model = in_sizes[2];        // 1024
  float* A32c  = (float*)d_ws;            // 16 KiB
  float* QROW  = (float*)d_ws + 4096;     // 16 KiB
  float* Q2ROW = (float*)d_ws + 8192;     // 16 KiB
  hippo_pow<<<64, 64, 0, stream>>>(ldt, A32c, QROW, Q2ROW);
  hippo_main<<<d_model, 256, 0, stream>>>(B, C, Dv, ldt, A32c, QROW, Q2ROW,
                                          (float*)d_out);
}